// Round 1
// baseline (352.596 us; speedup 1.0000x reference)
//
#include <hip/hip_runtime.h>
#include <math.h>

// Problem constants (fixed by the reference):
// S=2048, B=128, K=64, D=256, T=6, row = T+D = 262 floats.
#define S_DIM 2048
#define B_DIM 128
#define K_DIM 64
#define D_DIM 256
#define T_DIM 6
#define ROW_LEN (T_DIM + D_DIM) /* 262 */
#define LOG_2PI_F 1.8378770664093453f
#define RPB 16 /* rows per block; divides B so all rows in a block share s */

// Kernel 1: collapse the K-dim.  lw_k(x,y) is quadratic in (x,y):
//   lw_k = c0 + c1 x + c2 y + c3 x^2 + c4 xy + c5 y^2
// emb[.,d] = sum_k W[d,k] lw_k = M[d] . phi(x,y), M = W @ C  (D x 6).
// Stored transposed Mt[j][d] so kernel 2 reads are wave-contiguous.
__global__ __launch_bounds__(256) void coef_kernel(
    const float* __restrict__ means,  // (K,2)
    const float* __restrict__ A,      // (K,2,2)
    const float* __restrict__ W,      // (D,K)
    const float* __restrict__ bvec,   // (D,)
    float* __restrict__ Mt)           // (6,D) in d_ws
{
    __shared__ float c[6][K_DIM];
    int t = threadIdx.x;
    if (t < K_DIM) {
        float a00 = A[4*t+0], a01 = A[4*t+1], a10 = A[4*t+2], a11 = A[4*t+3];
        // cov = A A^T (symmetric 2x2)
        float cov00 = a00*a00 + a01*a01;
        float cov01 = a00*a10 + a01*a11;
        float cov11 = a10*a10 + a11*a11;
        float det   = cov00*cov11 - cov01*cov01;
        float rdet  = 1.0f / det;
        float i00 =  cov11*rdet, i01 = -cov01*rdet, i11 = cov00*rdet;
        float mx = means[2*t], my = means[2*t+1];
        // lw = -0.5*quad - 0.5*log(det) - LOG_2PI, quad expanded in x,y:
        c[0][t] = -0.5f*(i00*mx*mx + 2.0f*i01*mx*my + i11*my*my + logf(det)) - LOG_2PI_F;
        c[1][t] = i00*mx + i01*my;
        c[2][t] = i01*mx + i11*my;
        c[3][t] = -0.5f*i00;
        c[4][t] = -i01;
        c[5][t] = -0.5f*i11;
    }
    __syncthreads();
    int d = t; // 256 threads == D
    float m0 = 0.f, m1 = 0.f, m2 = 0.f, m3 = 0.f, m4 = 0.f, m5 = 0.f;
    const float* wrow = W + d*K_DIM;
#pragma unroll
    for (int k = 0; k < K_DIM; ++k) {
        float w = wrow[k];
        m0 += w*c[0][k]; m1 += w*c[1][k]; m2 += w*c[2][k];
        m3 += w*c[3][k]; m4 += w*c[4][k]; m5 += w*c[5][k];
    }
    Mt[0*D_DIM + d] = m0 + bvec[d]; // fold bias into constant term
    Mt[1*D_DIM + d] = m1;
    Mt[2*D_DIM + d] = m2;
    Mt[3*D_DIM + d] = m3;
    Mt[4*D_DIM + d] = m4;
    Mt[5*D_DIM + d] = m5;
}

// Kernel 2: streaming write of the (S,B,262) output.
// One block handles RPB consecutive rows (same s -> one pe load, M in regs).
// Lane t writes emb element d=t per row; lanes 0..5 also copy traj_feats.
__global__ __launch_bounds__(256) void emb_kernel(
    const float* __restrict__ traj,   // (S,B,T)
    const float* __restrict__ xy,     // (S,B,2)
    const float* __restrict__ pe,     // (MAX_LEN,1,D)
    const float* __restrict__ Mt,     // (6,D)
    float* __restrict__ out)          // (S,B,262)
{
    int t    = threadIdx.x;
    int row0 = blockIdx.x * RPB;
    int s    = row0 >> 7;             // B = 128
    float m0 = Mt[0*D_DIM + t], m1 = Mt[1*D_DIM + t], m2 = Mt[2*D_DIM + t];
    float m3 = Mt[3*D_DIM + t], m4 = Mt[4*D_DIM + t], m5 = Mt[5*D_DIM + t];
    float p  = pe[s*D_DIM + t];
#pragma unroll
    for (int r = 0; r < RPB; ++r) {
        int row = row0 + r;
        float x = xy[2*row + 0];      // block-uniform -> scalar loads
        float y = xy[2*row + 1];
        float v = m0 + m1*x + m2*y + (m3*x + m4*y)*x + m5*y*y + p;
        size_t base = (size_t)row * ROW_LEN;
        out[base + T_DIM + t] = v;
        if (t < T_DIM) out[base + t] = traj[row*T_DIM + t];
    }
}

extern "C" void kernel_launch(void* const* d_in, const int* in_sizes, int n_in,
                              void* d_out, int out_size, void* d_ws, size_t ws_size,
                              hipStream_t stream) {
    const float* traj  = (const float*)d_in[0]; // (S,B,T)
    const float* xy    = (const float*)d_in[1]; // (S,B,2)
    const float* means = (const float*)d_in[2]; // (K,2)
    const float* A     = (const float*)d_in[3]; // (K,2,2)
    const float* W     = (const float*)d_in[4]; // (D,K)
    const float* bvec  = (const float*)d_in[5]; // (D,)
    const float* pe    = (const float*)d_in[6]; // (MAX_LEN,1,D)
    float* out = (float*)d_out;
    float* Mt  = (float*)d_ws; // 6*D*4 = 6 KB

    coef_kernel<<<1, 256, 0, stream>>>(means, A, W, bvec, Mt);

    int nrows = S_DIM * B_DIM;           // 262144
    int grid  = nrows / RPB;             // 16384 blocks
    emb_kernel<<<grid, 256, 0, stream>>>(traj, xy, pe, Mt, out);
}

// Round 2
// 296.573 us; speedup vs baseline: 1.1889x; 1.1889x over previous
//
#include <hip/hip_runtime.h>
#include <math.h>

// Problem constants (fixed by the reference):
// S=2048, B=128, K=64, D=256, T=6, row = T+D = 262 floats.
#define S_DIM 2048
#define B_DIM 128
#define K_DIM 64
#define D_DIM 256
#define T_DIM 6
#define ROW_LEN (T_DIM + D_DIM) /* 262 */
#define LOG_2PI_F 1.8378770664093453f
#define RPB 16 /* rows per block; 16 | 128 so all rows in a block share s */
// 16 rows * 262 floats = 4192 floats = 16768 B = 131 x 128B lines exactly,
// and the block's output base (blockIdx*16768 B) is 16B-aligned -> clean float4 stores.

// Kernel 1: collapse the K-dim.  lw_k(x,y) is quadratic in (x,y):
//   lw_k = c0 + c1 x + c2 y + c3 x^2 + c4 xy + c5 y^2
// emb[.,d] = sum_k W[d,k] lw_k = M[d] . phi(x,y), M = W @ C  (D x 6).
// Stored transposed Mt[j][d] so kernel 2 reads are wave-contiguous.
__global__ __launch_bounds__(256) void coef_kernel(
    const float* __restrict__ means,  // (K,2)
    const float* __restrict__ A,      // (K,2,2)
    const float* __restrict__ W,      // (D,K)
    const float* __restrict__ bvec,   // (D,)
    float* __restrict__ Mt)           // (6,D) in d_ws
{
    __shared__ float c[6][K_DIM];
    int t = threadIdx.x;
    if (t < K_DIM) {
        float a00 = A[4*t+0], a01 = A[4*t+1], a10 = A[4*t+2], a11 = A[4*t+3];
        // cov = A A^T (symmetric 2x2)
        float cov00 = a00*a00 + a01*a01;
        float cov01 = a00*a10 + a01*a11;
        float cov11 = a10*a10 + a11*a11;
        float det   = cov00*cov11 - cov01*cov01;
        float rdet  = 1.0f / det;
        float i00 =  cov11*rdet, i01 = -cov01*rdet, i11 = cov00*rdet;
        float mx = means[2*t], my = means[2*t+1];
        // lw = -0.5*quad - 0.5*log(det) - LOG_2PI, quad expanded in x,y:
        c[0][t] = -0.5f*(i00*mx*mx + 2.0f*i01*mx*my + i11*my*my + logf(det)) - LOG_2PI_F;
        c[1][t] = i00*mx + i01*my;
        c[2][t] = i01*mx + i11*my;
        c[3][t] = -0.5f*i00;
        c[4][t] = -i01;
        c[5][t] = -0.5f*i11;
    }
    __syncthreads();
    int d = t; // 256 threads == D
    float m0 = 0.f, m1 = 0.f, m2 = 0.f, m3 = 0.f, m4 = 0.f, m5 = 0.f;
    const float* wrow = W + d*K_DIM;
#pragma unroll
    for (int k = 0; k < K_DIM; ++k) {
        float w = wrow[k];
        m0 += w*c[0][k]; m1 += w*c[1][k]; m2 += w*c[2][k];
        m3 += w*c[3][k]; m4 += w*c[4][k]; m5 += w*c[5][k];
    }
    Mt[0*D_DIM + d] = m0 + bvec[d]; // fold bias into constant term
    Mt[1*D_DIM + d] = m1;
    Mt[2*D_DIM + d] = m2;
    Mt[3*D_DIM + d] = m3;
    Mt[4*D_DIM + d] = m4;
    Mt[5*D_DIM + d] = m5;
}

// Kernel 2: stage 16 rows in LDS in final layout, then aligned float4 copy-out.
__global__ __launch_bounds__(256) void emb_kernel(
    const float* __restrict__ traj,   // (S,B,T)
    const float* __restrict__ xy,     // (S,B,2)
    const float* __restrict__ pe,     // (MAX_LEN,1,D)
    const float* __restrict__ Mt,     // (6,D)
    float* __restrict__ out)          // (S,B,262)
{
    __shared__ float tile[RPB * ROW_LEN]; // 4192 floats = 16768 B
    __shared__ float xys[2 * RPB];        // x,y per row

    int t    = threadIdx.x;
    int blk  = blockIdx.x;
    int row0 = blk * RPB;
    int s    = row0 >> 7;                 // B = 128

    // Cooperative vector loads: 8 float4 of xy (wave 0), 24 float4 of traj (wave 1).
    if (t < 8) {                          // xy tile: 32 floats, base blk*128 B (16B aligned)
        float4 v = ((const float4*)xy)[blk * 8 + t];
        ((float4*)xys)[t] = v;
    }
    if (t >= 64 && t < 88) {              // traj tile: 96 floats, base blk*384 B (16B aligned)
        int i = t - 64;
        float4 v = ((const float4*)traj)[blk * 24 + i];
        int j = i * 4;                    // flat index in 16x6 traj tile
        tile[(j    / T_DIM) * ROW_LEN + (j    % T_DIM)] = v.x;
        tile[((j+1)/ T_DIM) * ROW_LEN + ((j+1)% T_DIM)] = v.y;
        tile[((j+2)/ T_DIM) * ROW_LEN + ((j+2)% T_DIM)] = v.z;
        tile[((j+3)/ T_DIM) * ROW_LEN + ((j+3)% T_DIM)] = v.w;
    }

    // Per-thread rank-6 coefficients (d = t), pe folded into the constant term.
    float m0 = Mt[0*D_DIM + t] + pe[s*D_DIM + t];
    float m1 = Mt[1*D_DIM + t], m2 = Mt[2*D_DIM + t];
    float m3 = Mt[3*D_DIM + t], m4 = Mt[4*D_DIM + t], m5 = Mt[5*D_DIM + t];

    __syncthreads();

    // Phase 1: evaluate emb for 16 rows into LDS (lane-consecutive writes: conflict-free).
#pragma unroll
    for (int r = 0; r < RPB; ++r) {
        float x = xys[2*r], y = xys[2*r + 1];   // broadcast reads
        float v = m0 + m1*x + m2*y + (m3*x + m4*y)*x + m5*y*y;
        tile[r * ROW_LEN + T_DIM + t] = v;
    }

    __syncthreads();

    // Phase 2: straight aligned float4 copy LDS -> global. 1048 float4s = 4*256 + 24.
    const float4* t4 = (const float4*)tile;
    float4* o4 = (float4*)(out + (size_t)row0 * ROW_LEN);
#pragma unroll
    for (int k = 0; k < 4; ++k)
        o4[k * 256 + t] = t4[k * 256 + t];
    if (t < 24)
        o4[1024 + t] = t4[1024 + t];
}

extern "C" void kernel_launch(void* const* d_in, const int* in_sizes, int n_in,
                              void* d_out, int out_size, void* d_ws, size_t ws_size,
                              hipStream_t stream) {
    const float* traj  = (const float*)d_in[0]; // (S,B,T)
    const float* xy    = (const float*)d_in[1]; // (S,B,2)
    const float* means = (const float*)d_in[2]; // (K,2)
    const float* A     = (const float*)d_in[3]; // (K,2,2)
    const float* W     = (const float*)d_in[4]; // (D,K)
    const float* bvec  = (const float*)d_in[5]; // (D,)
    const float* pe    = (const float*)d_in[6]; // (MAX_LEN,1,D)
    float* out = (float*)d_out;
    float* Mt  = (float*)d_ws; // 6*D*4 = 6 KB

    coef_kernel<<<1, 256, 0, stream>>>(means, A, W, bvec, Mt);

    int nrows = S_DIM * B_DIM;           // 262144
    int grid  = nrows / RPB;             // 16384 blocks
    emb_kernel<<<grid, 256, 0, stream>>>(traj, xy, pe, Mt, out);
}

// Round 3
// 292.960 us; speedup vs baseline: 1.2036x; 1.0123x over previous
//
#include <hip/hip_runtime.h>
#include <math.h>

// Problem constants (fixed by the reference):
// S=2048, B=128, K=64, D=256, T=6, row = T+D = 262 floats.
#define S_DIM 2048
#define B_DIM 128
#define K_DIM 64
#define D_DIM 256
#define T_DIM 6
#define ROW_LEN (T_DIM + D_DIM) /* 262 */
#define LOG_2PI_F 1.8378770664093453f
#define RPB 32 /* rows per block; 32 | 128 so all rows in a block share s */

typedef float v4f __attribute__((ext_vector_type(4)));

// ---------------------------------------------------------------------------
// Kernel 1: collapse the K-dim.  lw_k(x,y) is quadratic in (x,y):
//   lw_k = c0 + c1 x + c2 y + c3 x^2 + c4 xy + c5 y^2
// emb[.,d] = sum_k W[d,k] lw_k = M[d] . phi(x,y), M = W @ C  (D x 6).
// Grid = 16 blocks x 256 threads; thread t -> (d = blk*16 + t/16, q = t%16).
// W read is ((float4*)W)[blk*256 + t]: one fully-coalesced pass.
// Reduction over the 16 lanes of each d-group via __shfl_xor (1,2,4,8).
// ---------------------------------------------------------------------------
__global__ __launch_bounds__(256) void coef_kernel(
    const float* __restrict__ means,  // (K,2)
    const float* __restrict__ A,      // (K,2,2)
    const float* __restrict__ W,      // (D,K)
    const float* __restrict__ bvec,   // (D,)
    float* __restrict__ Mt)           // (6,D) in d_ws
{
    __shared__ float c[6][K_DIM];
    int t = threadIdx.x;
    if (t < K_DIM) {
        float a00 = A[4*t+0], a01 = A[4*t+1], a10 = A[4*t+2], a11 = A[4*t+3];
        float cov00 = a00*a00 + a01*a01;            // cov = A A^T (symmetric)
        float cov01 = a00*a10 + a01*a11;
        float cov11 = a10*a10 + a11*a11;
        float det   = cov00*cov11 - cov01*cov01;
        float rdet  = 1.0f / det;
        float i00 =  cov11*rdet, i01 = -cov01*rdet, i11 = cov00*rdet;
        float mx = means[2*t], my = means[2*t+1];
        c[0][t] = -0.5f*(i00*mx*mx + 2.0f*i01*mx*my + i11*my*my + logf(det)) - LOG_2PI_F;
        c[1][t] = i00*mx + i01*my;
        c[2][t] = i01*mx + i11*my;
        c[3][t] = -0.5f*i00;
        c[4][t] = -i01;
        c[5][t] = -0.5f*i11;
    }
    __syncthreads();

    int d = blockIdx.x * 16 + (t >> 4);   // one d per 16 lanes
    int q = t & 15;                       // this lane's k-quad (k = 4q..4q+3)
    float4 w = ((const float4*)W)[blockIdx.x * 256 + t]; // = W[d][4q..4q+3]

    float m[6];
#pragma unroll
    for (int j = 0; j < 6; ++j) {
        const float* cj = &c[j][4*q];
        m[j] = w.x*cj[0] + w.y*cj[1] + w.z*cj[2] + w.w*cj[3];
        // reduce across the 16 lanes of this d-group (lane-aligned groups)
        m[j] += __shfl_xor(m[j], 1);
        m[j] += __shfl_xor(m[j], 2);
        m[j] += __shfl_xor(m[j], 4);
        m[j] += __shfl_xor(m[j], 8);
    }
    if (q == 0) {
        Mt[0*D_DIM + d] = m[0] + bvec[d]; // fold bias into constant term
#pragma unroll
        for (int j = 1; j < 6; ++j)
            Mt[j*D_DIM + d] = m[j];
    }
}

// ---------------------------------------------------------------------------
// Kernel 2: stage 32 rows in LDS in final layout, then aligned nontemporal
// float4 copy-out (the 274 MB write stream bypasses L2, which keeps serving
// the Mt/pe re-reads).
// ---------------------------------------------------------------------------
__global__ __launch_bounds__(256) void emb_kernel(
    const float* __restrict__ traj,   // (S,B,T)
    const float* __restrict__ xy,     // (S,B,2)
    const float* __restrict__ pe,     // (MAX_LEN,1,D)
    const float* __restrict__ Mt,     // (6,D)
    float* __restrict__ out)          // (S,B,262)
{
    __shared__ float tile[RPB * ROW_LEN]; // 8384 floats = 33536 B
    __shared__ float xys[2 * RPB];        // x,y per row

    int t    = threadIdx.x;
    int blk  = blockIdx.x;
    int row0 = blk * RPB;
    int s    = row0 >> 7;                 // B = 128; 32 | 128 -> uniform s

    // Cooperative vector loads: 16 float4 of xy (wave 0), 48 float4 of traj (wave 1).
    if (t < 16) {                         // xy tile: 64 floats, base blk*256 B
        float4 v = ((const float4*)xy)[blk * 16 + t];
        ((float4*)xys)[t] = v;
    }
    if (t >= 64 && t < 112) {             // traj tile: 192 floats, base blk*768 B
        int i = t - 64;
        float4 v = ((const float4*)traj)[blk * 48 + i];
        int j = i * 4;                    // flat index in 32x6 traj tile
        tile[(j    / T_DIM) * ROW_LEN + (j    % T_DIM)] = v.x;
        tile[((j+1)/ T_DIM) * ROW_LEN + ((j+1)% T_DIM)] = v.y;
        tile[((j+2)/ T_DIM) * ROW_LEN + ((j+2)% T_DIM)] = v.z;
        tile[((j+3)/ T_DIM) * ROW_LEN + ((j+3)% T_DIM)] = v.w;
    }

    // Per-thread rank-6 coefficients (d = t), pe folded into the constant term.
    float m0 = Mt[0*D_DIM + t] + pe[s*D_DIM + t];
    float m1 = Mt[1*D_DIM + t], m2 = Mt[2*D_DIM + t];
    float m3 = Mt[3*D_DIM + t], m4 = Mt[4*D_DIM + t], m5 = Mt[5*D_DIM + t];

    __syncthreads();

    // Phase 1: evaluate emb for 32 rows into LDS (lane-consecutive: conflict-free).
#pragma unroll
    for (int r = 0; r < RPB; ++r) {
        float x = xys[2*r], y = xys[2*r + 1];   // broadcast reads
        float v = m0 + m1*x + m2*y + (m3*x + m4*y)*x + m5*y*y;
        tile[r * ROW_LEN + T_DIM + t] = v;
    }

    __syncthreads();

    // Phase 2: aligned nontemporal float4 copy LDS -> global.
    // 32*262 = 8384 floats = 2096 float4 = 8*256 + 48.
    const v4f* t4 = (const v4f*)tile;
    v4f* o4 = (v4f*)(out + (size_t)row0 * ROW_LEN); // base blk*33536 B, 16B-aligned
#pragma unroll
    for (int k = 0; k < 8; ++k)
        __builtin_nontemporal_store(t4[k * 256 + t], &o4[k * 256 + t]);
    if (t < 48)
        __builtin_nontemporal_store(t4[2048 + t], &o4[2048 + t]);
}

extern "C" void kernel_launch(void* const* d_in, const int* in_sizes, int n_in,
                              void* d_out, int out_size, void* d_ws, size_t ws_size,
                              hipStream_t stream) {
    const float* traj  = (const float*)d_in[0]; // (S,B,T)
    const float* xy    = (const float*)d_in[1]; // (S,B,2)
    const float* means = (const float*)d_in[2]; // (K,2)
    const float* A     = (const float*)d_in[3]; // (K,2,2)
    const float* W     = (const float*)d_in[4]; // (D,K)
    const float* bvec  = (const float*)d_in[5]; // (D,)
    const float* pe    = (const float*)d_in[6]; // (MAX_LEN,1,D)
    float* out = (float*)d_out;
    float* Mt  = (float*)d_ws; // 6*D*4 = 6 KB

    coef_kernel<<<16, 256, 0, stream>>>(means, A, W, bvec, Mt);

    int nrows = S_DIM * B_DIM;           // 262144
    int grid  = nrows / RPB;             // 8192 blocks
    emb_kernel<<<grid, 256, 0, stream>>>(traj, xy, pe, Mt, out);
}